// Round 1
// 318.648 us; speedup vs baseline: 1.0324x; 1.0324x over previous
//
#include <hip/hip_runtime.h>

// Problem constants (B=8, T=4096, C=512)
#define BB 8
#define TT 4096
#define CC 512
#define MM (BB * TT)   // 32768 rows
#define SS 128         // scan chunks
#define LL 32          // steps per chunk (SS*LL == TT)

typedef short short8 __attribute__((ext_vector_type(8)));
typedef unsigned short ushort8 __attribute__((ext_vector_type(8)));
typedef float f32x4 __attribute__((ext_vector_type(4)));

__device__ __forceinline__ unsigned short f2bf(float f) {
    unsigned int u = __float_as_uint(f);
    u += 0x7FFFu + ((u >> 16) & 1u);   // RNE
    return (unsigned short)(u >> 16);
}
__device__ __forceinline__ float bf2f(unsigned short h) {
    return __uint_as_float(((unsigned int)h) << 16);
}

// async global->LDS, 16B per lane. LDS dest must be wave-uniform base + lane*16.
__device__ __forceinline__ void gl_lds16(const void* g, void* l) {
    __builtin_amdgcn_global_load_lds(
        (__attribute__((address_space(1))) void*)(unsigned long long)g,
        (__attribute__((address_space(3))) void*)(unsigned int)(unsigned long long)l,
        16, 0, 0);
}

__device__ __forceinline__ ushort8 pack8(f32x4 a, f32x4 b) {
    ushort8 r;
    r[0] = f2bf(a.x); r[1] = f2bf(a.y); r[2] = f2bf(a.z); r[3] = f2bf(a.w);
    r[4] = f2bf(b.x); r[5] = f2bf(b.y); r[6] = f2bf(b.z); r[7] = f2bf(b.w);
    return r;
}

// ---------------------------------------------------------------------------
// Kernel 1: transpose + bf16-convert the four 512x512 weights. wT[n][k]=w[k][n]
// ---------------------------------------------------------------------------
__global__ void transpose_w(const float* __restrict__ wk, const float* __restrict__ wv,
                            const float* __restrict__ wr, const float* __restrict__ wo,
                            unsigned short* __restrict__ wT) {
    const int which = blockIdx.y;
    const float* src = (which == 0) ? wk : (which == 1) ? wv : (which == 2) ? wr : wo;
    const int i = blockIdx.x * 256 + threadIdx.x;
    const int n = i >> 9;
    const int k = i & 511;
    wT[(size_t)which * (CC * CC) + i] = f2bf(src[(size_t)k * CC + n]);
}

// ---------------------------------------------------------------------------
// Kernel 2: time-shift mix for all three branches in one memory-bound pass.
// Writes bf16 mixed activations into b1/b2/b3 (consumed by gemm_tile).
// ---------------------------------------------------------------------------
__global__ __launch_bounds__(256) void mix_kvr(
    const float* __restrict__ x,
    const float* __restrict__ mixk, const float* __restrict__ mixv,
    const float* __restrict__ mixr,
    unsigned short* __restrict__ kx, unsigned short* __restrict__ vx,
    unsigned short* __restrict__ rx) {
    const int idx = blockIdx.x * 256 + threadIdx.x;   // 0 .. MM*CC/8-1
    const int row = idx >> 6;
    const int ch  = (idx & 63) * 8;
    const int t   = row & (TT - 1);
    const size_t off = (size_t)row * CC + ch;
    const float* xr = x + off;

    const f32x4 zero4 = {0.f, 0.f, 0.f, 0.f};
    const f32x4 one4  = {1.f, 1.f, 1.f, 1.f};

    f32x4 xc0 = ((const f32x4*)xr)[0];
    f32x4 xc1 = ((const f32x4*)xr)[1];
    f32x4 xp0 = zero4, xp1 = zero4;
    if (t != 0) {
        xp0 = ((const f32x4*)(xr - CC))[0];
        xp1 = ((const f32x4*)(xr - CC))[1];
    }

    f32x4 m0, m1;
    m0 = ((const f32x4*)(mixk + ch))[0];
    m1 = ((const f32x4*)(mixk + ch))[1];
    *(ushort8*)(kx + off) = pack8(xc0 * m0 + xp0 * (one4 - m0),
                                  xc1 * m1 + xp1 * (one4 - m1));
    m0 = ((const f32x4*)(mixv + ch))[0];
    m1 = ((const f32x4*)(mixv + ch))[1];
    *(ushort8*)(vx + off) = pack8(xc0 * m0 + xp0 * (one4 - m0),
                                  xc1 * m1 + xp1 * (one4 - m1));
    m0 = ((const f32x4*)(mixr + ch))[0];
    m1 = ((const f32x4*)(mixr + ch))[1];
    *(ushort8*)(rx + off) = pack8(xc0 * m0 + xp0 * (one4 - m0),
                                  xc1 * m1 + xp1 * (one4 - m1));
}

// ---------------------------------------------------------------------------
// Kernel 3: out-of-place GEMM, 128x256 tile, double-buffered LDS, 2-phase
// stage-ahead (T3 minimum recipe), conflict-free XOR swizzle.
//   A: [M][512] bf16, Bw: wT panel [512][512] bf16 (row n = output col),
//   Out: [M][512] bf16 (sigmoid applied if sig).
// grid = (MM/128, 2). Block = 256 thr = 4 waves in 2x2; wave tile 64x128.
// LDS swizzle: 16B col-group g of row r stored at slot g ^ ((r>>1)&3).
// 16 lanes of a ds_read_b128 then cover the 8 distinct (row-parity x
// col-group) bank slots exactly twice -> 2-way aliasing, which is free.
// ---------------------------------------------------------------------------
#define STAGE_KVR(bufidx, k0) do {                                              \
    gl_lds16(agA + (k0), &As[bufidx][tid * 8]);                                 \
    gl_lds16(agA + (size_t)64 * CC + (k0), &As[bufidx][(256 + tid) * 8]);       \
    _Pragma("unroll")                                                           \
    for (int s_ = 0; s_ < 4; ++s_)                                              \
        gl_lds16(agB + (size_t)(s_ * 64) * CC + (k0),                           \
                 &Bs[bufidx][(s_ * 256 + tid) * 8]);                            \
} while (0)

__global__ __launch_bounds__(256, 2) void gemm_tile(
    const unsigned short* __restrict__ A,
    const unsigned short* __restrict__ Bw,
    unsigned short* __restrict__ Out,
    const int sig) {
    __shared__ unsigned short As[2][128 * 32];    // 2 x  8 KiB
    __shared__ unsigned short Bs[2][256 * 32];    // 2 x 16 KiB

    const int tid = threadIdx.x;
    const int pm = blockIdx.x;   // 0..255
    const int pn = blockIdx.y;   // 0..1

    // staging: seg = s*256+tid covers row (s*64 + tid>>2), 16B col-group tid&3.
    // source col-group is swizzled: cg = (tid&3) ^ ((row>>1)&3); row>>1 low
    // bits = (tid>>3)&3 (s*64 and 64-row strides are 0 mod 8).
    const int ar = tid >> 2;                        // 0..63
    const int cg = (tid & 3) ^ ((tid >> 3) & 3);
    const unsigned short* agA = A  + (size_t)(pm * 128 + ar) * CC + cg * 8;
    const unsigned short* agB = Bw + (size_t)(pn * 256 + ar) * CC + cg * 8;

    const int w = tid >> 6, lane = tid & 63;
    const int wr = w >> 1, wc = w & 1;
    const int q = lane >> 4, l16 = lane & 15;
    const int sw = (q ^ ((l16 >> 1) & 3)) * 8;      // reader-side swizzle

    f32x4 acc[4][8];
#pragma unroll
    for (int i = 0; i < 4; i++)
#pragma unroll
        for (int j = 0; j < 8; j++) acc[i][j] = (f32x4){0.f, 0.f, 0.f, 0.f};

    STAGE_KVR(0, 0);
    __syncthreads();

    for (int kt = 0; kt < 16; ++kt) {
        const int cur = kt & 1;
        if (kt + 1 < 16) {
            const int nxt = cur ^ 1;
            const int k0 = (kt + 1) * 32;
            STAGE_KVR(nxt, k0);
        }

        short8 a[4], b[8];
#pragma unroll
        for (int i = 0; i < 4; i++)
            a[i] = *(const short8*)&As[cur][(wr * 64 + i * 16 + l16) * 32 + sw];
#pragma unroll
        for (int j = 0; j < 8; j++)
            b[j] = *(const short8*)&Bs[cur][(wc * 128 + j * 16 + l16) * 32 + sw];
#pragma unroll
        for (int i = 0; i < 4; i++)
#pragma unroll
            for (int j = 0; j < 8; j++)
                acc[i][j] = __builtin_amdgcn_mfma_f32_16x16x32_bf16(a[i], b[j], acc[i][j], 0, 0, 0);

        // drains vmcnt(0): next buffer staged; lgkmcnt(0): all reads of cur done
        __syncthreads();
    }

    // epilogue: row = wr*64 + i*16 + q*4 + ii, col = pn*256 + wc*128 + j*16 + l16
    const size_t rb = (size_t)pm * 128 + wr * 64;
    const int nb = pn * 256 + wc * 128;
#pragma unroll
    for (int i = 0; i < 4; i++)
#pragma unroll
        for (int j = 0; j < 8; j++)
#pragma unroll
            for (int ii = 0; ii < 4; ii++) {
                const int m = i * 16 + q * 4 + ii;
                const int n = nb + j * 16 + l16;
                float val = acc[i][j][ii];
                if (sig) val = 1.0f / (1.0f + __expf(-val));
                Out[(rb + m) * CC + n] = f2bf(val);
            }
}

// ---------------------------------------------------------------------------
// WKV chunked parallel scan (unchanged).
// ---------------------------------------------------------------------------
__global__ __launch_bounds__(256) void wkv_part1(
    const unsigned short* __restrict__ kb, const unsigned short* __restrict__ vb,
    const float* __restrict__ sd,
    float* __restrict__ sp_, float* __restrict__ sq_, float* __restrict__ so_) {
    const int idx = blockIdx.x * 256 + threadIdx.x;
    const int c = idx & (CC - 1);
    const int b = (idx >> 9) & (BB - 1);
    const int s = idx >> 12;
    const float w = sd[c] * (1.0f / (float)TT);
    const size_t base = ((size_t)b * TT + (size_t)s * LL) * CC + c;
    const unsigned short* kp = kb + base;
    const unsigned short* vp = vb + base;

    float p = 0.f, q = 0.f, o = -1e38f;
#pragma unroll 8
    for (int i = 0; i < LL; ++i) {
        const float kt = bf2f(kp[(size_t)i * CC]);
        const float vt = bf2f(vp[(size_t)i * CC]);
        const float no2 = fmaxf(w + o, kt);
        const float A2  = __expf(w + o - no2);
        const float B2  = __expf(kt - no2);
        p = A2 * p + B2 * vt;
        q = A2 * q + B2;
        o = no2;
    }
    sp_[idx] = p; sq_[idx] = q; so_[idx] = o;
}

__global__ __launch_bounds__(256) void wkv_part2(
    const float* __restrict__ sd,
    float* __restrict__ sp_, float* __restrict__ sq_, float* __restrict__ so_) {
    const int idx = blockIdx.x * 256 + threadIdx.x;
    const int c = idx & (CC - 1);
    const float wL = sd[c] * ((float)LL / (float)TT);

    float p = 0.f, q = 0.f, o = -1e38f;
    float lp = sp_[idx], lq = sq_[idx], lo = so_[idx];
    for (int s = 0; s < SS; ++s) {
        const int off = s * (BB * CC) + idx;
        float nlp = 0.f, nlq = 0.f, nlo = 0.f;
        if (s + 1 < SS) {
            nlp = sp_[off + BB * CC];
            nlq = sq_[off + BB * CC];
            nlo = so_[off + BB * CC];
        }
        sp_[off] = p; sq_[off] = q; so_[off] = o;
        const float no = fmaxf(o + wL, lo);
        const float A  = __expf(o + wL - no);
        const float Bc = __expf(lo - no);
        p = A * p + Bc * lp;
        q = A * q + Bc * lq;
        o = no;
        lp = nlp; lq = nlq; lo = nlo;
    }
}

__global__ __launch_bounds__(256) void wkv_part3(
    const unsigned short* __restrict__ kb, const unsigned short* __restrict__ vb,
    const unsigned short* __restrict__ srb,
    const float* __restrict__ sd, const float* __restrict__ sf,
    const float* __restrict__ sp_, const float* __restrict__ sq_,
    const float* __restrict__ so_,
    unsigned short* __restrict__ zb) {
    const int idx = blockIdx.x * 256 + threadIdx.x;
    const int c = idx & (CC - 1);
    const int b = (idx >> 9) & (BB - 1);
    const int s = idx >> 12;
    const float w = sd[c] * (1.0f / (float)TT);
    const float u = sf[c] * (1.0f / (float)TT);
    const size_t base = ((size_t)b * TT + (size_t)s * LL) * CC + c;
    const unsigned short* kp = kb + base;
    const unsigned short* vp = vb + base;
    const unsigned short* sp = srb + base;
    unsigned short* zp = zb + base;

    float p = sp_[idx], q = sq_[idx], o = so_[idx];
#pragma unroll 4
    for (int i = 0; i < LL; ++i) {
        const float kt = bf2f(kp[(size_t)i * CC]);
        const float vt = bf2f(vp[(size_t)i * CC]);
        const float sr = bf2f(sp[(size_t)i * CC]);

        const float no = fmaxf(o, u + kt);
        const float A  = __expf(o - no);
        const float Bt = __expf(u + kt - no);
        const float y  = (A * p + Bt * vt) / (A * q + Bt);
        zp[(size_t)i * CC] = f2bf(sr * y);

        const float no2 = fmaxf(w + o, kt);
        const float A2  = __expf(w + o - no2);
        const float B2  = __expf(kt - no2);
        p = A2 * p + B2 * vt;
        q = A2 * q + B2;
        o = no2;
    }
}

// ---------------------------------------------------------------------------
// Kernel 4: out = z @ wo. Same 128x256 dbuf structure, fp32 output.
// ---------------------------------------------------------------------------
__global__ __launch_bounds__(256, 2) void gemm_out(
    const unsigned short* __restrict__ zb, const unsigned short* __restrict__ woT,
    float* __restrict__ out) {
    __shared__ unsigned short As[2][128 * 32];
    __shared__ unsigned short Bs[2][256 * 32];

    const int tid = threadIdx.x;
    const int pm = blockIdx.x;
    const int pn = blockIdx.y;

    const int ar = tid >> 2;
    const int cg = (tid & 3) ^ ((tid >> 3) & 3);
    const unsigned short* agA = zb  + (size_t)(pm * 128 + ar) * CC + cg * 8;
    const unsigned short* agB = woT + (size_t)(pn * 256 + ar) * CC + cg * 8;

    const int w = tid >> 6, lane = tid & 63;
    const int wr = w >> 1, wc = w & 1;
    const int q = lane >> 4, l16 = lane & 15;
    const int sw = (q ^ ((l16 >> 1) & 3)) * 8;

    f32x4 acc[4][8];
#pragma unroll
    for (int i = 0; i < 4; i++)
#pragma unroll
        for (int j = 0; j < 8; j++) acc[i][j] = (f32x4){0.f, 0.f, 0.f, 0.f};

    STAGE_KVR(0, 0);
    __syncthreads();

    for (int kt = 0; kt < 16; ++kt) {
        const int cur = kt & 1;
        if (kt + 1 < 16) {
            const int nxt = cur ^ 1;
            const int k0 = (kt + 1) * 32;
            STAGE_KVR(nxt, k0);
        }

        short8 a[4], b[8];
#pragma unroll
        for (int i = 0; i < 4; i++)
            a[i] = *(const short8*)&As[cur][(wr * 64 + i * 16 + l16) * 32 + sw];
#pragma unroll
        for (int j = 0; j < 8; j++)
            b[j] = *(const short8*)&Bs[cur][(wc * 128 + j * 16 + l16) * 32 + sw];
#pragma unroll
        for (int i = 0; i < 4; i++)
#pragma unroll
            for (int j = 0; j < 8; j++)
                acc[i][j] = __builtin_amdgcn_mfma_f32_16x16x32_bf16(a[i], b[j], acc[i][j], 0, 0, 0);

        __syncthreads();
    }

    const size_t rb = (size_t)pm * 128 + wr * 64;
    const int nb = pn * 256 + wc * 128;
#pragma unroll
    for (int i = 0; i < 4; i++)
#pragma unroll
        for (int j = 0; j < 8; j++)
#pragma unroll
            for (int ii = 0; ii < 4; ii++) {
                const int m = i * 16 + q * 4 + ii;
                const int n = nb + j * 16 + l16;
                out[(rb + m) * CC + n] = acc[i][j][ii];
            }
}

// ---------------------------------------------------------------------------
extern "C" void kernel_launch(void* const* d_in, const int* in_sizes, int n_in,
                              void* d_out, int out_size, void* d_ws, size_t ws_size,
                              hipStream_t stream) {
    const float* x  = (const float*)d_in[0];
    const float* sd = (const float*)d_in[1];
    const float* sf = (const float*)d_in[2];
    const float* mk = (const float*)d_in[3];
    const float* mv = (const float*)d_in[4];
    const float* mr = (const float*)d_in[5];
    const float* wk = (const float*)d_in[6];
    const float* wv = (const float*)d_in[7];
    const float* wr = (const float*)d_in[8];
    const float* wo = (const float*)d_in[9];
    float* out = (float*)d_out;

    // ws layout (136 MiB total; ws ceiling is in [194,200) MiB):
    //   wT    bf16 [4][512][512]  2 MiB
    //   b1..b4 bf16 [M][C]       4 x 32 MiB  (buffer rotation, see below)
    //   sp/sq/so fp32 [S][B][C]  3 x 2 MiB
    //
    // Rotation (out-of-place GEMM, stream-serialized so no races):
    //   mix:  x -> b1 (xk), b2 (xv), b3 (xr)
    //   gemm: b1 @ wk -> b4 (k);  b2 @ wv -> b1 (v);  b3 @ wr -> b2 (sr)
    //   wkv:  (b4, b1, b2) -> b3 (z)
    //   out:  b3 @ wo -> out
    char* ws = (char*)d_ws;
    unsigned short* wT = (unsigned short*)ws;
    unsigned short* b1 = (unsigned short*)(ws + (size_t)4 * CC * CC * 2);
    unsigned short* b2 = b1 + (size_t)MM * CC;
    unsigned short* b3 = b2 + (size_t)MM * CC;
    unsigned short* b4 = b3 + (size_t)MM * CC;
    float* sp_ = (float*)(b4 + (size_t)MM * CC);
    float* sq_ = sp_ + (size_t)SS * BB * CC;
    float* so_ = sq_ + (size_t)SS * BB * CC;
    unsigned short* woT = wT + (size_t)3 * CC * CC;

    transpose_w<<<dim3((CC * CC) / 256, 4), 256, 0, stream>>>(wk, wv, wr, wo, wT);

    mix_kvr<<<dim3((MM * CC / 8) / 256), 256, 0, stream>>>(
        x, mk, mv, mr, b1, b2, b3);

    gemm_tile<<<dim3(MM / 128, 2), 256, 0, stream>>>(b1, wT + (size_t)0 * CC * CC, b4, 0);
    gemm_tile<<<dim3(MM / 128, 2), 256, 0, stream>>>(b2, wT + (size_t)1 * CC * CC, b1, 0);
    gemm_tile<<<dim3(MM / 128, 2), 256, 0, stream>>>(b3, wT + (size_t)2 * CC * CC, b2, 1);

    wkv_part1<<<dim3((SS * BB * CC) / 256), 256, 0, stream>>>(b4, b1, sd, sp_, sq_, so_);
    wkv_part2<<<dim3((BB * CC) / 256), 256, 0, stream>>>(sd, sp_, sq_, so_);
    wkv_part3<<<dim3((SS * BB * CC) / 256), 256, 0, stream>>>(
        b4, b1, b2, sd, sf, sp_, sq_, so_, b3);

    gemm_out<<<dim3(MM / 128, 2), 256, 0, stream>>>(b3, woT, out);
}

// Round 2
// 295.635 us; speedup vs baseline: 1.1127x; 1.0778x over previous
//
#include <hip/hip_runtime.h>

// Problem constants (B=8, T=4096, C=512)
#define BB 8
#define TT 4096
#define CC 512
#define MM (BB * TT)   // 32768 rows
#define SS 128         // scan chunks
#define LL 32          // steps per chunk (SS*LL == TT)

typedef short short8 __attribute__((ext_vector_type(8)));
typedef unsigned short ushort8 __attribute__((ext_vector_type(8)));
typedef float f32x4 __attribute__((ext_vector_type(4)));

__device__ __forceinline__ unsigned short f2bf(float f) {
    unsigned int u = __float_as_uint(f);
    u += 0x7FFFu + ((u >> 16) & 1u);   // RNE
    return (unsigned short)(u >> 16);
}
__device__ __forceinline__ float bf2f(unsigned short h) {
    return __uint_as_float(((unsigned int)h) << 16);
}

// async global->LDS, 16B per lane. LDS dest must be wave-uniform base + lane*16.
__device__ __forceinline__ void gl_lds16(const void* g, void* l) {
    __builtin_amdgcn_global_load_lds(
        (__attribute__((address_space(1))) void*)(unsigned long long)g,
        (__attribute__((address_space(3))) void*)(unsigned int)(unsigned long long)l,
        16, 0, 0);
}

__device__ __forceinline__ ushort8 pack8(f32x4 a, f32x4 b) {
    ushort8 r;
    r[0] = f2bf(a.x); r[1] = f2bf(a.y); r[2] = f2bf(a.z); r[3] = f2bf(a.w);
    r[4] = f2bf(b.x); r[5] = f2bf(b.y); r[6] = f2bf(b.z); r[7] = f2bf(b.w);
    return r;
}

// ---------------------------------------------------------------------------
// Kernel 1: transpose + bf16-convert the four 512x512 weights. wT[n][k]=w[k][n]
// LDS-tiled (64x64) so both global read and write are coalesced.
// ---------------------------------------------------------------------------
__global__ __launch_bounds__(256) void transpose_w(
    const float* __restrict__ wk, const float* __restrict__ wv,
    const float* __restrict__ wr, const float* __restrict__ wo,
    unsigned short* __restrict__ wT) {
    __shared__ float t[64][65];
    const int which = blockIdx.z;
    const float* src = (which == 0) ? wk : (which == 1) ? wv : (which == 2) ? wr : wo;
    const int k0 = blockIdx.y * 64;        // source row block
    const int n0 = blockIdx.x * 64;        // source col block
    const int r = threadIdx.x >> 6;        // 0..3
    const int c = threadIdx.x & 63;        // 0..63
#pragma unroll
    for (int p = 0; p < 16; ++p)
        t[p * 4 + r][c] = src[(size_t)(k0 + p * 4 + r) * CC + n0 + c];
    __syncthreads();
    unsigned short* dst = wT + (size_t)which * (CC * CC);
#pragma unroll
    for (int p = 0; p < 16; ++p)
        dst[(size_t)(n0 + p * 4 + r) * CC + k0 + c] = f2bf(t[c][p * 4 + r]);
}

// ---------------------------------------------------------------------------
// Kernel 2: time-shift mix for all three branches in one memory-bound pass.
// ---------------------------------------------------------------------------
__global__ __launch_bounds__(256) void mix_kvr(
    const float* __restrict__ x,
    const float* __restrict__ mixk, const float* __restrict__ mixv,
    const float* __restrict__ mixr,
    unsigned short* __restrict__ kx, unsigned short* __restrict__ vx,
    unsigned short* __restrict__ rx) {
    const int idx = blockIdx.x * 256 + threadIdx.x;   // 0 .. MM*CC/8-1
    const int row = idx >> 6;
    const int ch  = (idx & 63) * 8;
    const int t   = row & (TT - 1);
    const size_t off = (size_t)row * CC + ch;
    const float* xr = x + off;

    const f32x4 zero4 = {0.f, 0.f, 0.f, 0.f};
    const f32x4 one4  = {1.f, 1.f, 1.f, 1.f};

    f32x4 xc0 = ((const f32x4*)xr)[0];
    f32x4 xc1 = ((const f32x4*)xr)[1];
    f32x4 xp0 = zero4, xp1 = zero4;
    if (t != 0) {
        xp0 = ((const f32x4*)(xr - CC))[0];
        xp1 = ((const f32x4*)(xr - CC))[1];
    }

    f32x4 m0, m1;
    m0 = ((const f32x4*)(mixk + ch))[0];
    m1 = ((const f32x4*)(mixk + ch))[1];
    *(ushort8*)(kx + off) = pack8(xc0 * m0 + xp0 * (one4 - m0),
                                  xc1 * m1 + xp1 * (one4 - m1));
    m0 = ((const f32x4*)(mixv + ch))[0];
    m1 = ((const f32x4*)(mixv + ch))[1];
    *(ushort8*)(vx + off) = pack8(xc0 * m0 + xp0 * (one4 - m0),
                                  xc1 * m1 + xp1 * (one4 - m1));
    m0 = ((const f32x4*)(mixr + ch))[0];
    m1 = ((const f32x4*)(mixr + ch))[1];
    *(ushort8*)(rx + off) = pack8(xc0 * m0 + xp0 * (one4 - m0),
                                  xc1 * m1 + xp1 * (one4 - m1));
}

// ---------------------------------------------------------------------------
// GEMM body: 128x256 tile, 3-deep LDS pipeline, counted vmcnt, raw barriers.
//   A: [M][512] bf16, Bw: wT panel (row n = output col), K = 512, BK = 32.
// Per K-step kt: STAGE(kt+2) | vmcnt(12) | barrier | ds_read buf[kt%3] |
//                lgkmcnt(0) | barrier | setprio(1) 32xMFMA setprio(0)
// vmcnt(12) = 2 stages x 6 loads still in flight => own stage(kt) landed;
// barrier-A makes that true for ALL waves. lgkmcnt(0)+barrier-B retires all
// reads of buf[kt%3] before any wave's next-iter STAGE overwrites it.
// LDS swizzle identical to the round-1 verified kernel (2-way max on read).
// ---------------------------------------------------------------------------
template <bool F32OUT>
__device__ __forceinline__ void gemm_body(
    const unsigned short* __restrict__ A,
    const unsigned short* __restrict__ Bw,
    void* __restrict__ OutP, const int sig,
    const int pm, const int pn) {
    __shared__ unsigned short As[3][128 * 32];    // 3 x  8 KiB
    __shared__ unsigned short Bs[3][256 * 32];    // 3 x 16 KiB

    const int tid = threadIdx.x;
    // staging: seg = s*256+tid covers row (s*64 + tid>>2), 16B col-group tid&3.
    // source col-group swizzled: cg = (tid&3) ^ ((row>>1)&3).
    const int ar = tid >> 2;                        // 0..63
    const int cg = (tid & 3) ^ ((tid >> 3) & 3);
    const unsigned short* agA = A  + (size_t)(pm * 128 + ar) * CC + cg * 8;
    const unsigned short* agB = Bw + (size_t)(pn * 256 + ar) * CC + cg * 8;

    const int w = tid >> 6, lane = tid & 63;
    const int wr = w >> 1, wc = w & 1;
    const int q = lane >> 4, l16 = lane & 15;
    const int sw = (q ^ ((l16 >> 1) & 3)) * 8;      // reader-side swizzle

    f32x4 acc[4][8];
#pragma unroll
    for (int i = 0; i < 4; i++)
#pragma unroll
        for (int j = 0; j < 8; j++) acc[i][j] = (f32x4){0.f, 0.f, 0.f, 0.f};

#define STG(bi, k0) do {                                                        \
    gl_lds16(agA + (k0), &As[bi][tid * 8]);                                     \
    gl_lds16(agA + (size_t)64 * CC + (k0), &As[bi][(256 + tid) * 8]);           \
    gl_lds16(agB + (k0),                    &Bs[bi][(0 * 256 + tid) * 8]);      \
    gl_lds16(agB + (size_t)64  * CC + (k0), &Bs[bi][(1 * 256 + tid) * 8]);      \
    gl_lds16(agB + (size_t)128 * CC + (k0), &Bs[bi][(2 * 256 + tid) * 8]);      \
    gl_lds16(agB + (size_t)192 * CC + (k0), &Bs[bi][(3 * 256 + tid) * 8]);      \
} while (0)

    STG(0, 0);
    STG(1, 32);

#pragma unroll
    for (int kt = 0; kt < 16; ++kt) {
        const int bi = kt % 3;                      // compile-time (unrolled)
        if (kt + 2 < 16) STG((kt + 2) % 3, (kt + 2) * 32);

        if (kt < 14)       asm volatile("s_waitcnt vmcnt(12)" ::: "memory");
        else if (kt == 14) asm volatile("s_waitcnt vmcnt(6)" ::: "memory");
        else               asm volatile("s_waitcnt vmcnt(0)" ::: "memory");
        __builtin_amdgcn_s_barrier();               // buf[bi] ready for all

        short8 a[4], b[8];
#pragma unroll
        for (int i = 0; i < 4; i++)
            a[i] = *(const short8*)&As[bi][(wr * 64 + i * 16 + l16) * 32 + sw];
#pragma unroll
        for (int j = 0; j < 8; j++)
            b[j] = *(const short8*)&Bs[bi][(wc * 128 + j * 16 + l16) * 32 + sw];
        asm volatile("s_waitcnt lgkmcnt(0)" ::: "memory");
        __builtin_amdgcn_s_barrier();               // reads retired for all

        __builtin_amdgcn_s_setprio(1);
#pragma unroll
        for (int i = 0; i < 4; i++)
#pragma unroll
            for (int j = 0; j < 8; j++)
                acc[i][j] = __builtin_amdgcn_mfma_f32_16x16x32_bf16(a[i], b[j], acc[i][j], 0, 0, 0);
        __builtin_amdgcn_s_setprio(0);
    }
#undef STG

    // epilogue: row = wr*64 + i*16 + q*4 + ii, col = pn*256 + wc*128 + j*16 + l16
    const size_t rb = (size_t)pm * 128 + wr * 64;
    const int nb = pn * 256 + wc * 128;
    if constexpr (F32OUT) {
        float* Out = (float*)OutP;
#pragma unroll
        for (int i = 0; i < 4; i++)
#pragma unroll
            for (int j = 0; j < 8; j++)
#pragma unroll
                for (int ii = 0; ii < 4; ii++) {
                    const int m = i * 16 + q * 4 + ii;
                    const int n = nb + j * 16 + l16;
                    Out[(rb + m) * CC + n] = acc[i][j][ii];
                }
    } else {
        unsigned short* Out = (unsigned short*)OutP;
#pragma unroll
        for (int i = 0; i < 4; i++)
#pragma unroll
            for (int j = 0; j < 8; j++)
#pragma unroll
                for (int ii = 0; ii < 4; ii++) {
                    const int m = i * 16 + q * 4 + ii;
                    const int n = nb + j * 16 + l16;
                    float val = acc[i][j][ii];
                    if (sig) val = 1.0f / (1.0f + __expf(-val));
                    Out[(rb + m) * CC + n] = f2bf(val);
                }
    }
}

// ---------------------------------------------------------------------------
// Kernel 3: all three branch GEMMs in ONE dispatch (blockIdx.y picks branch).
// XCD pairing swizzle: the two pn-blocks sharing an A panel land on the same
// XCD chunk (512 blocks % 8 == 0, bijective m157 mapping).
// ---------------------------------------------------------------------------
__global__ __launch_bounds__(256, 2) void gemm_kvr3(
    const unsigned short* __restrict__ wT,
    const unsigned short* __restrict__ A0, const unsigned short* __restrict__ A1,
    const unsigned short* __restrict__ A2,
    unsigned short* __restrict__ O0, unsigned short* __restrict__ O1,
    unsigned short* __restrict__ O2) {
    const int z = blockIdx.y;
    const int lin = blockIdx.x;
    const int wg = (lin & 7) * 64 + (lin >> 3);
    const int pm = wg >> 1, pn = wg & 1;
    const unsigned short* A = (z == 0) ? A0 : (z == 1) ? A1 : A2;
    unsigned short* O = (z == 0) ? O0 : (z == 1) ? O1 : O2;
    gemm_body<false>(A, wT + (size_t)z * (CC * CC), O, z == 2, pm, pn);
}

// ---------------------------------------------------------------------------
// Kernel 4: out = z @ wo (fp32 output), same pipeline.
// ---------------------------------------------------------------------------
__global__ __launch_bounds__(256, 2) void gemm_out(
    const unsigned short* __restrict__ zb, const unsigned short* __restrict__ woT,
    float* __restrict__ out) {
    const int lin = blockIdx.x;
    const int wg = (lin & 7) * 64 + (lin >> 3);
    gemm_body<true>(zb, woT, out, 0, wg >> 1, wg & 1);
}

// ---------------------------------------------------------------------------
// WKV chunked parallel scan (unchanged).
// ---------------------------------------------------------------------------
__global__ __launch_bounds__(256) void wkv_part1(
    const unsigned short* __restrict__ kb, const unsigned short* __restrict__ vb,
    const float* __restrict__ sd,
    float* __restrict__ sp_, float* __restrict__ sq_, float* __restrict__ so_) {
    const int idx = blockIdx.x * 256 + threadIdx.x;
    const int c = idx & (CC - 1);
    const int b = (idx >> 9) & (BB - 1);
    const int s = idx >> 12;
    const float w = sd[c] * (1.0f / (float)TT);
    const size_t base = ((size_t)b * TT + (size_t)s * LL) * CC + c;
    const unsigned short* kp = kb + base;
    const unsigned short* vp = vb + base;

    float p = 0.f, q = 0.f, o = -1e38f;
#pragma unroll 8
    for (int i = 0; i < LL; ++i) {
        const float kt = bf2f(kp[(size_t)i * CC]);
        const float vt = bf2f(vp[(size_t)i * CC]);
        const float no2 = fmaxf(w + o, kt);
        const float A2  = __expf(w + o - no2);
        const float B2  = __expf(kt - no2);
        p = A2 * p + B2 * vt;
        q = A2 * q + B2;
        o = no2;
    }
    sp_[idx] = p; sq_[idx] = q; so_[idx] = o;
}

__global__ __launch_bounds__(256) void wkv_part2(
    const float* __restrict__ sd,
    float* __restrict__ sp_, float* __restrict__ sq_, float* __restrict__ so_) {
    const int idx = blockIdx.x * 256 + threadIdx.x;
    const int c = idx & (CC - 1);
    const float wL = sd[c] * ((float)LL / (float)TT);

    float p = 0.f, q = 0.f, o = -1e38f;
    float lp = sp_[idx], lq = sq_[idx], lo = so_[idx];
    for (int s = 0; s < SS; ++s) {
        const int off = s * (BB * CC) + idx;
        float nlp = 0.f, nlq = 0.f, nlo = 0.f;
        if (s + 1 < SS) {
            nlp = sp_[off + BB * CC];
            nlq = sq_[off + BB * CC];
            nlo = so_[off + BB * CC];
        }
        sp_[off] = p; sq_[off] = q; so_[off] = o;
        const float no = fmaxf(o + wL, lo);
        const float A  = __expf(o + wL - no);
        const float Bc = __expf(lo - no);
        p = A * p + Bc * lp;
        q = A * q + Bc * lq;
        o = no;
        lp = nlp; lq = nlq; lo = nlo;
    }
}

__global__ __launch_bounds__(256) void wkv_part3(
    const unsigned short* __restrict__ kb, const unsigned short* __restrict__ vb,
    const unsigned short* __restrict__ srb,
    const float* __restrict__ sd, const float* __restrict__ sf,
    const float* __restrict__ sp_, const float* __restrict__ sq_,
    const float* __restrict__ so_,
    unsigned short* __restrict__ zb) {
    const int idx = blockIdx.x * 256 + threadIdx.x;
    const int c = idx & (CC - 1);
    const int b = (idx >> 9) & (BB - 1);
    const int s = idx >> 12;
    const float w = sd[c] * (1.0f / (float)TT);
    const float u = sf[c] * (1.0f / (float)TT);
    const size_t base = ((size_t)b * TT + (size_t)s * LL) * CC + c;
    const unsigned short* kp = kb + base;
    const unsigned short* vp = vb + base;
    const unsigned short* sp = srb + base;
    unsigned short* zp = zb + base;

    float p = sp_[idx], q = sq_[idx], o = so_[idx];
#pragma unroll 4
    for (int i = 0; i < LL; ++i) {
        const float kt = bf2f(kp[(size_t)i * CC]);
        const float vt = bf2f(vp[(size_t)i * CC]);
        const float sr = bf2f(sp[(size_t)i * CC]);

        const float no = fmaxf(o, u + kt);
        const float A  = __expf(o - no);
        const float Bt = __expf(u + kt - no);
        const float y  = (A * p + Bt * vt) / (A * q + Bt);
        zp[(size_t)i * CC] = f2bf(sr * y);

        const float no2 = fmaxf(w + o, kt);
        const float A2  = __expf(w + o - no2);
        const float B2  = __expf(kt - no2);
        p = A2 * p + B2 * vt;
        q = A2 * q + B2;
        o = no2;
    }
}

// ---------------------------------------------------------------------------
extern "C" void kernel_launch(void* const* d_in, const int* in_sizes, int n_in,
                              void* d_out, int out_size, void* d_ws, size_t ws_size,
                              hipStream_t stream) {
    const float* x  = (const float*)d_in[0];
    const float* sd = (const float*)d_in[1];
    const float* sf = (const float*)d_in[2];
    const float* mk = (const float*)d_in[3];
    const float* mv = (const float*)d_in[4];
    const float* mr = (const float*)d_in[5];
    const float* wk = (const float*)d_in[6];
    const float* wv = (const float*)d_in[7];
    const float* wr = (const float*)d_in[8];
    const float* wo = (const float*)d_in[9];
    float* out = (float*)d_out;

    // ws layout (168 MiB total; ws ceiling is in [194,200) MiB):
    //   wT     bf16 [4][512][512]  2 MiB
    //   b1..b5 bf16 [M][C]         5 x 32 MiB
    //   sp/sq/so fp32 [S][B][C]    3 x 2 MiB
    //
    // Rotation (one fused GEMM dispatch -> all 3 outputs need fresh buffers;
    // sigmoid(r) goes to d_out used as bf16 scratch, overwritten by gemm_out):
    //   mix:  x -> b1 (xk), b2 (xv), b3 (xr)
    //   gemm: b1@wk -> b4 (k) ; b2@wv -> b5 (v) ; b3@wr -> srS=d_out (sr)
    //   wkv:  (b4, b5, srS) -> b1 (z)
    //   out:  b1 @ wo -> out (fp32, overwrites srS region)
    char* ws = (char*)d_ws;
    unsigned short* wT = (unsigned short*)ws;
    unsigned short* b1 = wT + (size_t)4 * CC * CC;
    unsigned short* b2 = b1 + (size_t)MM * CC;
    unsigned short* b3 = b2 + (size_t)MM * CC;
    unsigned short* b4 = b3 + (size_t)MM * CC;
    unsigned short* b5 = b4 + (size_t)MM * CC;
    float* sp_ = (float*)(b5 + (size_t)MM * CC);
    float* sq_ = sp_ + (size_t)SS * BB * CC;
    float* so_ = sq_ + (size_t)SS * BB * CC;
    unsigned short* woT = wT + (size_t)3 * CC * CC;
    unsigned short* srS = (unsigned short*)d_out;   // bf16 scratch inside out

    transpose_w<<<dim3(8, 8, 4), 256, 0, stream>>>(wk, wv, wr, wo, wT);

    mix_kvr<<<dim3((MM * CC / 8) / 256), 256, 0, stream>>>(
        x, mk, mv, mr, b1, b2, b3);

    gemm_kvr3<<<dim3(512, 3), 256, 0, stream>>>(wT, b1, b2, b3, b4, b5, srS);

    wkv_part1<<<dim3((SS * BB * CC) / 256), 256, 0, stream>>>(b4, b5, sd, sp_, sq_, so_);
    wkv_part2<<<dim3((BB * CC) / 256), 256, 0, stream>>>(sd, sp_, sq_, so_);
    wkv_part3<<<dim3((SS * BB * CC) / 256), 256, 0, stream>>>(
        b4, b5, srS, sd, sf, sp_, sq_, so_, b1);

    gemm_out<<<dim3(512), 256, 0, stream>>>(b1, woT, out);
}